// Round 7
// baseline (95.040 us; speedup 1.0000x reference)
//
#include <hip/hip_runtime.h>
#include <cfloat>

#define KC     32768
#define NPTS   8192
#define RCODES 16                  // codes per lane
#define SLABS  (KC / (64 * RCODES))   // 32
#define PGRP   (NPTS / 64)            // 128 point-groups of 64
#define NBLK   ((SLABS * PGRP) / 4)   // 1024 blocks x 4 waves

typedef float v2f __attribute__((ext_vector_type(2)));

// Packed fp32 (IEEE per 32-bit half) — bit-identical to scalar chain (verified R1-R4)
__device__ __forceinline__ v2f pk_mul(v2f a, v2f b) {
    v2f d; asm("v_pk_mul_f32 %0, %1, %2" : "=v"(d) : "v"(a), "v"(b)); return d;
}
__device__ __forceinline__ v2f pk_fma(v2f a, v2f b, v2f c) {
    v2f d; asm("v_pk_fma_f32 %0, %1, %2, %3" : "=v"(d) : "v"(a), "v"(b), "v"(c)); return d;
}
__device__ __forceinline__ v2f pk_add(v2f a, v2f b) {
    v2f d; asm("v_pk_add_f32 %0, %1, %2" : "=v"(d) : "v"(a), "v"(b)); return d;
}
__device__ __forceinline__ float min3f(float a, float b, float c) {
    float d; asm("v_min3_f32 %0, %1, %2, %3" : "=v"(d) : "v"(a), "v"(b), "v"(c)); return d;
}

// One DPP min step. Boundary-safe chain: only bcast15/31 have invalid source
// lanes, and their (possibly-corrupted) lanes never feed lane 63's chain.
template<int CTRL>
__device__ __forceinline__ float dpp_min(float v) {
    int vi = __float_as_int(v);
    int mv = __builtin_amdgcn_update_dpp(vi, vi, CTRL, 0xF, 0xF, false);
    return fminf(v, __int_as_float(mv));
}

// ---------------- K1: codes-in-registers; wave owns a 1024-code slab
__global__ __launch_bounds__(256, 4) void k_dist(const float* __restrict__ x,
                                                 const float* __restrict__ E,
                                                 float2* __restrict__ dk) {
#pragma clang fp contract(off)
    const int lane = threadIdx.x & 63;
    const int w    = blockIdx.x * 4 + (threadIdx.x >> 6);
    const int slab = w >> 7;            // 0..31 (waves in a block share a slab)
    const int pg   = w & 127;           // 0..127
    const int cb   = slab * 1024 + lane * RCODES;   // lane-major: low lane = low k

    // Load 16 codes, repack to cross-code v2f pairs, bnorm exact:
    // ((x^2+y^2)+z^2)+w^2 with squares individually rounded (R1-verified)
    v2f ex[8], ey[8], ez[8], ew[8], eb[8];
#pragma unroll
    for (int u = 0; u < 8; ++u) {
        float4 c0 = ((const float4*)E)[cb + 2 * u];
        float4 c1 = ((const float4*)E)[cb + 2 * u + 1];
        ex[u] = v2f{c0.x, c1.x};
        ey[u] = v2f{c0.y, c1.y};
        ez[u] = v2f{c0.z, c1.z};
        ew[u] = v2f{c0.w, c1.w};
        v2f sx = pk_mul(ex[u], ex[u]);
        v2f sy = pk_mul(ey[u], ey[u]);
        v2f sz = pk_mul(ez[u], ez[u]);
        v2f sw = pk_mul(ew[u], ew[u]);
        eb[u] = pk_add(pk_add(pk_add(sx, sy), sz), sw);
    }
    const v2f M2 = {-2.0f, -2.0f};

    float bd_out = 0.0f;
    int   bk_out = 0;
    const int pbase = pg * 64;

    for (int j = 0; j < 64; ++j) {
        const int p  = pbase + j;            // wave-uniform point
        const int t  = p >> 12, s = p & 4095;
        const int xb = t * 16384 + s;
        const float x0 = x[xb];
        const float x1 = x[xb + 4096];
        const float x2 = x[xb + 8192];
        const float x3 = x[xb + 12288];
        const float a  = ((x0 * x0 + x1 * x1) + x2 * x2) + x3 * x3;
        const v2f X0 = {x0, x0}, X1 = {x1, x1}, X2 = {x2, x2}, X3 = {x3, x3};
        const v2f Av = {a, a};

        float bd = FLT_MAX;
        int rloc = 0;
#pragma unroll
        for (int q = 0; q < 4; ++q) {
            v2f m0 = pk_fma(X3, ew[2*q],   pk_fma(X2, ez[2*q],   pk_fma(X1, ey[2*q],   pk_mul(X0, ex[2*q]))));
            v2f m1 = pk_fma(X3, ew[2*q+1], pk_fma(X2, ez[2*q+1], pk_fma(X1, ey[2*q+1], pk_mul(X0, ex[2*q+1]))));
            v2f d0 = pk_fma(M2, m0, pk_add(Av, eb[2*q]));
            v2f d1 = pk_fma(M2, m1, pk_add(Av, eb[2*q+1]));
            // tournament min + first-index equality select == sequential strict-<
            float bd4 = min3f(min3f(bd, d0.x, d0.y), d1.x, d1.y);
            int sel = (d1.x == bd4) ? 2 : 3;
            sel = (d0.y == bd4) ? 1 : sel;
            sel = (d0.x == bd4) ? 0 : sel;
            rloc = (bd4 != bd) ? (4 * q + sel) : rloc;   // tie -> keep earlier
            bd = bd4;
        }

        // cross-lane min: 6 DPP steps, collector = lane 63
        float v = bd;
        v = dpp_min<0xB1>(v);    // quad_perm [1,0,3,2]  (xor 1)
        v = dpp_min<0x4E>(v);    // quad_perm [2,3,0,1]  (xor 2)
        v = dpp_min<0x141>(v);   // row_half_mirror      (merge 8)
        v = dpp_min<0x140>(v);   // row_mirror           (merge 16)
        v = dpp_min<0x142>(v);   // row_bcast15          (merge 32)
        v = dpp_min<0x143>(v);   // row_bcast31          (merge 64)
        const int   dmin_i = __builtin_amdgcn_readlane(__float_as_int(v), 63);
        const float dmin   = __int_as_float(dmin_i);

        // first lane holding dmin == smallest k (lane-major layout)
        const unsigned long long msk = __ballot(bd == dmin);
        const int win  = __ffsll((unsigned long long)msk) - 1;
        const int kwin = __builtin_amdgcn_readlane(cb + rloc, win);

        // park in lane j (uniform dmin/kwin -> cmp + 2 cndmask, no writelane)
        const bool mine = (lane == j);
        bd_out = mine ? dmin : bd_out;
        bk_out = mine ? kwin : bk_out;
    }

    float2 o;
    o.x = bd_out;
    o.y = __int_as_float(bk_out);
    dk[slab * NPTS + pbase + lane] = o;   // coalesced: one float2 per lane
}

// ---------------- K2: merge slabs, gather, z_q_st, per-block loss partial
__global__ __launch_bounds__(64) void k_final(const float* __restrict__ x,
                                              const float* __restrict__ E,
                                              const float2* __restrict__ dk,
                                              float* __restrict__ out,
                                              double* __restrict__ partials) {
#pragma clang fp contract(off)
    const int tid = threadIdx.x;
    const int p   = blockIdx.x * 64 + tid;     // 128 blocks x 64 threads
    const int t   = p >> 12;
    const int s   = p & 4095;

    float bd = FLT_MAX;
    int   bk = 0;
    for (int c = 0; c < SLABS; ++c) {          // increasing k ranges
        float2 v = dk[c * NPTS + p];
        if (v.x < bd) { bd = v.x; bk = __float_as_int(v.y); }  // strict <
    }

    float4 e = ((const float4*)E)[bk];
    float ev[4] = {e.x, e.y, e.z, e.w};
    double ls = 0.0;
    const int xb = t * 16384 + s;
    for (int ch = 0; ch < 4; ++ch) {
        int idx = xb + ch * 4096;
        float xv   = x[idx];
        float diff = ev[ch] - xv;              // fl(z_q - x)
        float sq   = diff * diff;              // fl(diff^2)
        out[idx]   = xv + diff;                // z_q_st = fl(x + fl(z_q - x))
        ls += (double)sq;
    }
    out[32769 + p] = (float)bk;                // codes as float

    for (int o = 32; o > 0; o >>= 1) ls += __shfl_down(ls, o);
    if (tid == 0) partials[blockIdx.x] = ls;
}

// ---------------- K3: finalize qloss
__global__ void k_loss(const double* __restrict__ partials,
                       float* __restrict__ out) {
#pragma clang fp contract(off)
    if (threadIdx.x == 0 && blockIdx.x == 0) {
        double sum = 0.0;
        for (int i = 0; i < 128; ++i) sum += partials[i];
        float mu = (float)(sum * (1.0 / 32768.0));   // /32768 exact
        float q  = mu + 0.1f * mu;                   // mean1 + BETA*mean2
        out[32768] = q;
    }
}

extern "C" void kernel_launch(void* const* d_in, const int* in_sizes, int n_in,
                              void* d_out, int out_size, void* d_ws, size_t ws_size,
                              hipStream_t stream) {
    const float* x = (const float*)d_in[0];   // (1,2,4,64,64)
    const float* E = (const float*)d_in[1];   // (32768,4)
    float* out = (float*)d_out;               // 40961 floats

    char* ws = (char*)d_ws;
    double* partials = (double*)ws;                    // 1 KB
    float2* dk       = (float2*)(ws + 1024);           // 32*8192*8 = 2 MB

    k_dist<<<NBLK, 256, 0, stream>>>(x, E, dk);
    k_final<<<NPTS / 64, 64, 0, stream>>>(x, E, dk, out, partials);
    k_loss<<<1, 64, 0, stream>>>(partials, out);
}

// Round 8
// 83.337 us; speedup vs baseline: 1.1404x; 1.1404x over previous
//
#include <hip/hip_runtime.h>
#include <cfloat>

#define KC   32768
#define NPTS 8192
#define TPB  128
#define PPT  4
#define PTS_PER_BLK (TPB * PPT)        // 512
#define NPB  (NPTS / PTS_PER_BLK)      // 16

typedef float v2f __attribute__((ext_vector_type(2)));

// Packed fp32 (IEEE per 32-bit half) — bit-identical to scalar chain (verified R1-R4)
__device__ __forceinline__ v2f pk_mul(v2f a, v2f b) {
    v2f d; asm("v_pk_mul_f32 %0, %1, %2" : "=v"(d) : "v"(a), "v"(b)); return d;
}
__device__ __forceinline__ v2f pk_fma(v2f a, v2f b, v2f c) {
    v2f d; asm("v_pk_fma_f32 %0, %1, %2, %3" : "=v"(d) : "v"(a), "v"(b), "v"(c)); return d;
}
__device__ __forceinline__ v2f pk_add(v2f a, v2f b) {
    v2f d; asm("v_pk_add_f32 %0, %1, %2" : "=v"(d) : "v"(a), "v"(b)); return d;
}
__device__ __forceinline__ float min3f(float a, float b, float c) {
    float d; asm("v_min3_f32 %0, %1, %2, %3" : "=v"(d) : "v"(a), "v"(b), "v"(c)); return d;
}

// ---------------- K1: partial argmin over one code chunk, 4 points per thread
template<int CHUNK>
__global__ __launch_bounds__(TPB) void k_dist(const float* __restrict__ x,
                                              const float* __restrict__ E,
                                              float2* __restrict__ dk) {
#pragma clang fp contract(off)
    __shared__ __align__(16) float lds[5 * CHUNK];
    float* exL = lds;
    float* eyL = lds + CHUNK;
    float* ezL = lds + 2 * CHUNK;
    float* ewL = lds + 3 * CHUNK;
    float* bL  = lds + 4 * CHUNK;

    const int chunk = blockIdx.x;
    const int pblk  = blockIdx.y;
    const int tid   = threadIdx.x;
    const int kbase = chunk * CHUNK;

    // Stage SoA + fused bnorm (squares individually rounded, sequential adds)
    for (int i = tid; i < CHUNK; i += TPB) {
        float4 e = ((const float4*)E)[kbase + i];
        exL[i] = e.x; eyL[i] = e.y; ezL[i] = e.z; ewL[i] = e.w;
        bL[i]  = ((e.x * e.x + e.y * e.y) + e.z * e.z) + e.w * e.w;
    }
    __syncthreads();

    // 4 points per thread, stride TPB for coalesced x loads
    int p_[PPT];
    v2f X0[PPT], X1[PPT], X2[PPT], X3[PPT], Av[PPT];
#pragma unroll
    for (int i = 0; i < PPT; ++i) {
        const int p  = pblk * PTS_PER_BLK + i * TPB + tid;
        p_[i] = p;
        const int t  = p >> 12, s = p & 4095;
        const int xb = t * 16384 + s;
        const float x0 = x[xb];
        const float x1 = x[xb + 4096];
        const float x2 = x[xb + 8192];
        const float x3 = x[xb + 12288];
        const float a  = ((x0 * x0 + x1 * x1) + x2 * x2) + x3 * x3;
        X0[i] = v2f{x0, x0}; X1[i] = v2f{x1, x1};
        X2[i] = v2f{x2, x2}; X3[i] = v2f{x3, x3};
        Av[i] = v2f{a, a};
    }
    const v2f M2 = {-2.0f, -2.0f};

    float bd[PPT]; int bk[PPT];
#pragma unroll
    for (int i = 0; i < PPT; ++i) { bd[i] = FLT_MAX; bk[i] = 0; }

#pragma unroll 2
    for (int q = 0; q < CHUNK / 4; ++q) {      // 4 codes x 4 points per iter
        float4 vx = *(const float4*)(exL + 4 * q);
        float4 vy = *(const float4*)(eyL + 4 * q);
        float4 vz = *(const float4*)(ezL + 4 * q);
        float4 vw = *(const float4*)(ewL + 4 * q);
        float4 vb = *(const float4*)(bL  + 4 * q);

        const v2f ex0 = {vx.x, vx.y}, ex1 = {vx.z, vx.w};
        const v2f ey0 = {vy.x, vy.y}, ey1 = {vy.z, vy.w};
        const v2f ez0 = {vz.x, vz.y}, ez1 = {vz.z, vz.w};
        const v2f ew0 = {vw.x, vw.y}, ew1 = {vw.z, vw.w};
        const v2f b0  = {vb.x, vb.y}, b1  = {vb.z, vb.w};
        const int kq = kbase + 4 * q;

#pragma unroll
        for (int i = 0; i < PPT; ++i) {
            // m = fma(x3,ew, fma(x2,ez, fma(x1,ey, x0*ex)))  (BLAS chain, R1-verified)
            v2f m0 = pk_fma(X3[i], ew0, pk_fma(X2[i], ez0, pk_fma(X1[i], ey0, pk_mul(X0[i], ex0))));
            v2f m1 = pk_fma(X3[i], ew1, pk_fma(X2[i], ez1, pk_fma(X1[i], ey1, pk_mul(X0[i], ex1))));
            // fma(-2,m,(a+b)) == (a+b) - fl(2m) bitwise (2m exact, one rounding each)
            v2f d0 = pk_fma(M2, m0, pk_add(Av[i], b0));
            v2f d1 = pk_fma(M2, m1, pk_add(Av[i], b1));
            // tournament min + first-index equality select == sequential strict-<
            float bd4 = min3f(min3f(bd[i], d0.x, d0.y), d1.x, d1.y);
            int sel = (d1.x == bd4) ? 2 : 3;
            sel = (d0.y == bd4) ? 1 : sel;
            sel = (d0.x == bd4) ? 0 : sel;
            bk[i] = (bd4 != bd[i]) ? (kq + sel) : bk[i];   // tie -> keep earlier
            bd[i] = bd4;
        }
    }
#pragma unroll
    for (int i = 0; i < PPT; ++i)
        dk[chunk * NPTS + p_[i]] = make_float2(bd[i], __int_as_float(bk[i]));
}

// ---------------- K2: merge chunks, gather, z_q_st, per-block loss partial
__global__ __launch_bounds__(256) void k_final(const float* __restrict__ x,
                                               const float* __restrict__ E,
                                               const float2* __restrict__ dk,
                                               float* __restrict__ out,
                                               double* __restrict__ partials,
                                               int nc) {
#pragma clang fp contract(off)
    const int tid = threadIdx.x;
    const int p   = blockIdx.x * 256 + tid;    // 32 blocks x 256 threads
    const int t   = p >> 12;
    const int s   = p & 4095;

    float bd = FLT_MAX;
    int   bk = 0;
#pragma unroll 8
    for (int c = 0; c < nc; ++c) {             // increasing k ranges
        float2 v = dk[c * NPTS + p];
        if (v.x < bd) { bd = v.x; bk = __float_as_int(v.y); }  // strict <
    }

    float4 e = ((const float4*)E)[bk];
    float ev[4] = {e.x, e.y, e.z, e.w};
    double ls = 0.0;
    const int xb = t * 16384 + s;
#pragma unroll
    for (int ch = 0; ch < 4; ++ch) {
        int idx = xb + ch * 4096;
        float xv   = x[idx];
        float diff = ev[ch] - xv;              // fl(z_q - x)
        float sq   = diff * diff;              // fl(diff^2)
        out[idx]   = xv + diff;                // z_q_st = fl(x + fl(z_q - x))
        ls += (double)sq;
    }
    out[32769 + p] = (float)bk;                // codes as float

    __shared__ double sred[256];
    sred[tid] = ls;
    __syncthreads();
    for (int o = 128; o > 0; o >>= 1) {
        if (tid < o) sred[tid] += sred[tid + o];
        __syncthreads();
    }
    if (tid == 0) partials[blockIdx.x] = sred[0];
}

// ---------------- K3: finalize qloss
__global__ void k_loss(const double* __restrict__ partials,
                       float* __restrict__ out) {
#pragma clang fp contract(off)
    if (threadIdx.x == 0 && blockIdx.x == 0) {
        double sum = 0.0;
        for (int i = 0; i < 32; ++i) sum += partials[i];
        float mu = (float)(sum * (1.0 / 32768.0));   // /32768 exact
        float q  = mu + 0.1f * mu;                   // mean1 + BETA*mean2
        out[32768] = q;
    }
}

extern "C" void kernel_launch(void* const* d_in, const int* in_sizes, int n_in,
                              void* d_out, int out_size, void* d_ws, size_t ws_size,
                              hipStream_t stream) {
    const float* x = (const float*)d_in[0];   // (1,2,4,64,64)
    const float* E = (const float*)d_in[1];   // (32768,4)
    float* out = (float*)d_out;               // 40961 floats

    char* ws = (char*)d_ws;
    double* partials = (double*)ws;                    // 1 KB
    float2* dk       = (float2*)(ws + 1024);

    // NC=64 needs 1KB + 64*8192*8B = ~4.2MB (proven available in R4); else NC=32
    const size_t need64 = 1024 + (size_t)64 * NPTS * 8;
    if (ws_size >= need64) {
        dim3 g(64, NPB);
        k_dist<512><<<g, TPB, 0, stream>>>(x, E, dk);
        k_final<<<NPTS / 256, 256, 0, stream>>>(x, E, dk, out, partials, 64);
    } else {
        dim3 g(32, NPB);
        k_dist<1024><<<g, TPB, 0, stream>>>(x, E, dk);
        k_final<<<NPTS / 256, 256, 0, stream>>>(x, E, dk, out, partials, 32);
    }
    k_loss<<<1, 64, 0, stream>>>(partials, out);
}